// Round 9
// baseline (263.497 us; speedup 1.0000x reference)
//
#include <hip/hip_runtime.h>

// Problem dims (fixed by reference)
#define T_TOTAL (32 * 4096)   // B*S = 131072 tokens
#define FDIM 256
#define NG 2                  // groups
#define NN 128                // entries per group
#define DDIM 128              // group dim
#define EDIM 256              // embed dim

#define TAU 0.004f            // bf16x3-vs-f32 safety margin for argmax gap
#define CAP 16384             // max flagged (t,g) entries (expected ~1k)

typedef __attribute__((ext_vector_type(4))) float f32x4;
typedef __attribute__((ext_vector_type(8))) short short8;

// ---------------------------------------------------------------------------
// Kernel P (prep): CO = codebooks @ W_out slices ; BT = split-bf16 W^T ;
// zero flag counter. One block per (g,n) = 256 blocks x 256 threads.
// ---------------------------------------------------------------------------
__global__ __launch_bounds__(256) void prep_kernel(
    const float* __restrict__ codebooks,  // [2][128][128]
    const float* __restrict__ W_out,      // [256][256]
    const float* __restrict__ Wl,         // [2][128 k][128 n]
    float* __restrict__ CO,               // [2][128][256]
    short* __restrict__ BT,               // [2 lev][2 g][128 n][128 k]
    int* __restrict__ flag_count)
{
    const int gn  = blockIdx.x;           // g*128 + n
    const int g   = gn >> 7;
    const int tid = threadIdx.x;
    __shared__ float cb[DDIM];
    if (tid < DDIM) cb[tid] = codebooks[gn * DDIM + tid];
    if (tid >= 128) {
        const int k = tid - 128;
        const int n = gn & 127;
        const float x = Wl[((size_t)g * DDIM + k) * NN + n];
        const unsigned u = __float_as_uint(x);
        const float hi = __uint_as_float(u & 0xffff0000u);
        const unsigned u2 = __float_as_uint(x - hi);   // exact residual
        BT[(size_t)g * 16384 + n * 128 + k] = (short)(u >> 16);
        BT[32768 + (size_t)g * 16384 + n * 128 + k] = (short)(u2 >> 16);
    }
    if (gn == 0 && tid == 0) *flag_count = 0;
    __syncthreads();
    float acc = 0.f;
    const float* wcol = W_out + (g * DDIM) * EDIM + tid;
#pragma unroll 4
    for (int d = 0; d < DDIM; ++d) acc += cb[d] * wcol[d * EDIM];
    CO[gn * EDIM + tid] = acc;
}

// ---------------------------------------------------------------------------
// Kernel M (fused main): one block = one 16-token tile. 512 threads = 8 waves
// = (2 groups x 4 n-quarters). Each wave: 32 n x 16 tokens via bf16x3 MFMA,
// A-fragments streamed from L2 (BT is 128 KB, hot; per-lane pattern proven
// correct in round 7), features/gumbel from HBM. NO LDS in the MFMA loop.
// Then: partial top-2 -> 1.7 KB LDS exchange -> block argmax -> fused out
// gather-write. No min-waves launch bound (rounds 6/7: clamps cause spills).
// ---------------------------------------------------------------------------
__global__ __launch_bounds__(512) void pq_fused_kernel(
    const float* __restrict__ features,   // [T][256]
    const float* __restrict__ gumbel,     // [T][2][128]
    const short* __restrict__ BT,         // [2 lev][2 g][128 n][128 k]
    const float* __restrict__ bl,         // [2][128]
    const float* __restrict__ CO,         // [2][128][256]
    const float* __restrict__ b_out,      // [256]
    float* __restrict__ out,              // [T][256]
    float* __restrict__ idx_f,            // [T][2] float-encoded indices
    int* __restrict__ flag_count,
    int* __restrict__ flag_list)
{
    __shared__ float pm1[8][16];
    __shared__ float pm2[8][16];
    __shared__ int   pi1[8][16];
    __shared__ int   sidx[2][16];

    const int tid = threadIdx.x;
    const int w   = tid >> 6;     // wave 0..7
    const int g   = w >> 2;       // group
    const int nt2 = w & 3;        // n-quarter
    const int l   = tid & 63;
    const int q   = l & 15;       // token slot / A-row
    const int h   = l >> 4;       // k-octet selector / D-subrow
    const int tbase = blockIdx.x * 16;
    const int t   = tbase + q;

    const int n00 = nt2 * 32;
    const int n01 = n00 + 16;

    // ---- issue HBM loads first: features (full 128-k half-row) + gumbel
    const float* fp = features + (size_t)t * FDIM + g * DDIM + h * 8;
    f32x4 FA[8];
#pragma unroll
    for (int j = 0; j < 8; ++j)
        FA[j] = *reinterpret_cast<const f32x4*>(fp + (j >> 1) * 32 + (j & 1) * 4);

    const float* gp = gumbel + ((size_t)t * NG + g) * NN;
    const f32x4 G0 = *reinterpret_cast<const f32x4*>(gp + n00 + h * 4);
    const f32x4 G1 = *reinterpret_cast<const f32x4*>(gp + n01 + h * 4);

    // ---- A-fragment window (L2): lane reads BT[n = n0+q][k = ks*32+h*8..+7]
    const short* bt1 = BT + (size_t)g * 16384;          // level 1 (hi)
    const short* bt2 = bt1 + 32768;                     // level 2 (residual)

#define LDA(d10, d11, d20, d21, KS)                                             \
    d10 = *reinterpret_cast<const short8*>(bt1 + (n00 + q) * 128 + (KS) * 32 + h * 8); \
    d11 = *reinterpret_cast<const short8*>(bt1 + (n01 + q) * 128 + (KS) * 32 + h * 8); \
    d20 = *reinterpret_cast<const short8*>(bt2 + (n00 + q) * 128 + (KS) * 32 + h * 8); \
    d21 = *reinterpret_cast<const short8*>(bt2 + (n01 + q) * 128 + (KS) * 32 + h * 8);

#define SPLITB(KS)                                                              \
    {                                                                           \
        _Pragma("unroll")                                                       \
        for (int e = 0; e < 4; ++e) {                                           \
            const unsigned ua = __float_as_uint(FA[2 * (KS)][e]);               \
            const float ha = __uint_as_float(ua & 0xffff0000u);                 \
            const unsigned ra = __float_as_uint(FA[2 * (KS)][e] - ha);          \
            B1[e] = (short)(ua >> 16); B2[e] = (short)(ra >> 16);               \
            const unsigned ub = __float_as_uint(FA[2 * (KS) + 1][e]);           \
            const float hb = __uint_as_float(ub & 0xffff0000u);                 \
            const unsigned rb = __float_as_uint(FA[2 * (KS) + 1][e] - hb);      \
            B1[4 + e] = (short)(ub >> 16); B2[4 + e] = (short)(rb >> 16);       \
        }                                                                       \
    }

#define MM(a10, a11, a20, a21)                                                  \
    acc0 = __builtin_amdgcn_mfma_f32_16x16x32_bf16(a10, B1, acc0, 0, 0, 0);     \
    acc0 = __builtin_amdgcn_mfma_f32_16x16x32_bf16(a20, B1, acc0, 0, 0, 0);     \
    acc0 = __builtin_amdgcn_mfma_f32_16x16x32_bf16(a10, B2, acc0, 0, 0, 0);     \
    acc1 = __builtin_amdgcn_mfma_f32_16x16x32_bf16(a11, B1, acc1, 0, 0, 0);     \
    acc1 = __builtin_amdgcn_mfma_f32_16x16x32_bf16(a21, B1, acc1, 0, 0, 0);     \
    acc1 = __builtin_amdgcn_mfma_f32_16x16x32_bf16(a11, B2, acc1, 0, 0, 0);

    short8 Xa10, Xa11, Xa20, Xa21, Xb10, Xb11, Xb20, Xb21;
    short8 B1, B2;
    f32x4 acc0 = (f32x4){0.f, 0.f, 0.f, 0.f};
    f32x4 acc1 = (f32x4){0.f, 0.f, 0.f, 0.f};

    LDA(Xa10, Xa11, Xa20, Xa21, 0)
    // ks = 0 (prefetch ks=1)
    LDA(Xb10, Xb11, Xb20, Xb21, 1)
    SPLITB(0)
    MM(Xa10, Xa11, Xa20, Xa21)
    // ks = 1 (prefetch ks=2)
    LDA(Xa10, Xa11, Xa20, Xa21, 2)
    SPLITB(1)
    MM(Xb10, Xb11, Xb20, Xb21)
    // ks = 2 (prefetch ks=3)
    LDA(Xb10, Xb11, Xb20, Xb21, 3)
    SPLITB(2)
    MM(Xa10, Xa11, Xa20, Xa21)
    // ks = 3
    SPLITB(3)
    MM(Xb10, Xb11, Xb20, Xb21)
#undef LDA
#undef SPLITB
#undef MM

    // ---- epilogue: +bias +gumbel, per-lane top-2 over 8 n-values
    const f32x4 bv0 = *reinterpret_cast<const f32x4*>(bl + g * NN + n00 + h * 4);
    const f32x4 bv1 = *reinterpret_cast<const f32x4*>(bl + g * NN + n01 + h * 4);

    float m1 = -3.4e38f, m2 = -3.4e38f;
    int   i1 = 0;
#pragma unroll
    for (int r = 0; r < 4; ++r) {
        const float vv = acc0[r] + bv0[r] + G0[r];
        const int   n  = n00 + h * 4 + r;
        if (vv > m1) { m2 = m1; m1 = vv; i1 = n; }
        else         { m2 = fmaxf(m2, vv); }
    }
#pragma unroll
    for (int r = 0; r < 4; ++r) {
        const float vv = acc1[r] + bv1[r] + G1[r];
        const int   n  = n01 + h * 4 + r;
        if (vv > m1) { m2 = m1; m1 = vv; i1 = n; }
        else         { m2 = fmaxf(m2, vv); }
    }
    // reduce across the 4 h-lanes sharing this token
#pragma unroll
    for (int off = 16; off < 64; off <<= 1) {
        const float om1 = __shfl_xor(m1, off);
        const int   oi1 = __shfl_xor(i1, off);
        const float om2 = __shfl_xor(m2, off);
        if (om1 > m1)      { m2 = fmaxf(m1, om2); m1 = om1; i1 = oi1; }
        else if (om1 < m1) { m2 = fmaxf(m2, om1); }
        else               { m2 = m1; i1 = min(i1, oi1); }
    }
    if (h == 0) { pm1[w][q] = m1; pm2[w][q] = m2; pi1[w][q] = i1; }
    __syncthreads();

    // ---- block combine: 32 threads, one per (group, token)
    if (tid < 32) {
        const int gg  = tid >> 4;
        const int tok = tid & 15;
        const int wb  = gg * 4;
        float c1 = pm1[wb][tok], c2 = pm2[wb][tok];
        int   ci = pi1[wb][tok];
#pragma unroll
        for (int p = 1; p < 4; ++p) {
            const float a1 = pm1[wb + p][tok];
            const float a2 = pm2[wb + p][tok];
            const int   ai = pi1[wb + p][tok];
            if (a1 > c1)      { c2 = fmaxf(c1, a2); c1 = a1; ci = ai; }
            else if (a1 < c1) { c2 = fmaxf(c2, a1); }
            else              { c2 = c1; ci = min(ci, ai); }
        }
        idx_f[(size_t)(tbase + tok) * NG + gg] = (float)ci;
        sidx[gg][tok] = ci;
        if (c1 - c2 < TAU) {
            const int p = atomicAdd(flag_count, 1);
            if (p < CAP) flag_list[p] = (tbase + tok) * NG + gg;
        }
    }
    __syncthreads();

    // ---- fused out write: 32 threads per token, 2 float4 slots each
    {
        const int tok = tid >> 5;
        const int c   = tid & 31;
        const int i0  = sidx[0][tok];
        const int j1  = sidx[1][tok];
        const float* c0p = CO + (size_t)i0 * EDIM;
        const float* c1p = CO + (size_t)(NN + j1) * EDIM;
        float* op = out + (size_t)(tbase + tok) * EDIM;
#pragma unroll
        for (int jj = 0; jj < 2; ++jj) {
            const int e4 = c + jj * 32;
            const float4 a  = *reinterpret_cast<const float4*>(c0p + e4 * 4);
            const float4 b2 = *reinterpret_cast<const float4*>(c1p + e4 * 4);
            const float4 bo = *reinterpret_cast<const float4*>(b_out + e4 * 4);
            float4 o;
            o.x = a.x + b2.x + bo.x;
            o.y = a.y + b2.y + bo.y;
            o.z = a.z + b2.z + bo.z;
            o.w = a.w + b2.w + bo.w;
            *reinterpret_cast<float4*>(op + e4 * 4) = o;
        }
    }
}

// ---------------------------------------------------------------------------
// Kernel F (fixup): exact sequential-f32 fmaf recompute for flagged (t,g).
// ---------------------------------------------------------------------------
__global__ __launch_bounds__(128) void fixup_kernel(
    const float* __restrict__ features,
    const float* __restrict__ gumbel,
    const float* __restrict__ Wl,         // [2][128 k][128 n]
    const float* __restrict__ bl,
    float* __restrict__ idx_f,
    const int* __restrict__ flag_count,
    const int* __restrict__ flag_list)
{
    __shared__ float sm[2];
    __shared__ int   si[2];
    int total = *flag_count;
    if (total > CAP) total = CAP;
    const int n = threadIdx.x;

    for (int e = blockIdx.x; e < total; e += gridDim.x) {
        const int code = flag_list[e];
        const int t = code >> 1, g = code & 1;
        const float* fpr = features + (size_t)t * FDIM + g * DDIM;
        const float* wp  = Wl + (size_t)g * DDIM * NN + n;
        float dot = 0.f;
#pragma unroll 8
        for (int k = 0; k < DDIM; ++k) dot = fmaf(fpr[k], wp[(size_t)k * NN], dot);
        const float v = (dot + bl[g * NN + n]) + gumbel[((size_t)t * NG + g) * NN + n];

        float m = v; int bi = n;
#pragma unroll
        for (int off = 1; off < 64; off <<= 1) {
            const float om = __shfl_xor(m, off);
            const int   ob = __shfl_xor(bi, off);
            if (om > m || (om == m && ob < bi)) { m = om; bi = ob; }
        }
        if ((n & 63) == 0) { sm[n >> 6] = m; si[n >> 6] = bi; }
        __syncthreads();
        if (n == 0) {
            const float mA = sm[0], mB = sm[1];
            const int bA = si[0], bB = si[1];
            const int best = (mB > mA || (mB == mA && bB < bA)) ? bB : bA;
            idx_f[code] = (float)best;
        }
        __syncthreads();
    }
}

// ---------------------------------------------------------------------------
// Kernel X (outfix): rewrite out rows for flagged tokens from FINAL indices.
// Duplicate tokens (both groups flagged) write identical bytes — benign.
// ---------------------------------------------------------------------------
__global__ __launch_bounds__(64) void outfix_kernel(
    const float* __restrict__ CO,
    const float* __restrict__ b_out,
    const float* __restrict__ idx_f,
    const int* __restrict__ flag_count,
    const int* __restrict__ flag_list,
    float* __restrict__ out)
{
    int total = *flag_count;
    if (total > CAP) total = CAP;
    const int c = threadIdx.x;    // 0..63 float4 slots

    for (int e = blockIdx.x; e < total; e += gridDim.x) {
        const int t  = flag_list[e] >> 1;
        const int i0 = (int)idx_f[t * NG + 0];
        const int i1 = (int)idx_f[t * NG + 1];
        const float4 a  = *reinterpret_cast<const float4*>(CO + (size_t)i0 * EDIM + c * 4);
        const float4 b2 = *reinterpret_cast<const float4*>(CO + (size_t)(NN + i1) * EDIM + c * 4);
        const float4 bo = *reinterpret_cast<const float4*>(b_out + c * 4);
        float4 o;
        o.x = a.x + b2.x + bo.x;
        o.y = a.y + b2.y + bo.y;
        o.z = a.z + b2.z + bo.z;
        o.w = a.w + b2.w + bo.w;
        *reinterpret_cast<float4*>(out + (size_t)t * EDIM + c * 4) = o;
    }
}

// ---------------------------------------------------------------------------
extern "C" void kernel_launch(void* const* d_in, const int* in_sizes, int n_in,
                              void* d_out, int out_size, void* d_ws, size_t ws_size,
                              hipStream_t stream) {
    const float* features  = (const float*)d_in[0];  // [32,4096,256]
    const float* gumbel    = (const float*)d_in[1];  // [32,4096,2,128]
    const float* Wl        = (const float*)d_in[2];  // [2,128,128]
    const float* bl        = (const float*)d_in[3];  // [2,128]
    const float* codebooks = (const float*)d_in[4];  // [2,128,128]
    const float* W_out     = (const float*)d_in[5];  // [256,256]
    const float* b_out     = (const float*)d_in[6];  // [256]

    float* out   = (float*)d_out;                    // [T,256]
    float* idx_f = out + (size_t)T_TOTAL * EDIM;     // [T,2] float-encoded indices

    // ws layout: CO (256KB) | BT (128KB) | flag_count (pad 256B) | flag_list (64KB)
    char* ws = (char*)d_ws;
    float* CO         = (float*)ws;                        // 262144 B
    short* BT         = (short*)(ws + 262144);             // 131072 B
    int*   flag_count = (int*)(ws + 262144 + 131072);      // @393216
    int*   flag_list  = (int*)(ws + 393216 + 256);         // @393472, 64KB

    prep_kernel<<<NG * NN, 256, 0, stream>>>(codebooks, W_out, Wl, CO, BT, flag_count);
    pq_fused_kernel<<<T_TOTAL / 16, 512, 0, stream>>>(
        features, gumbel, BT, bl, CO, b_out, out, idx_f, flag_count, flag_list);
    fixup_kernel<<<1024, 128, 0, stream>>>(
        features, gumbel, Wl, bl, idx_f, flag_count, flag_list);
    outfix_kernel<<<1024, 64, 0, stream>>>(
        CO, b_out, idx_f, flag_count, flag_list, out);
}

// Round 10
// 209.963 us; speedup vs baseline: 1.2550x; 1.2550x over previous
//
#include <hip/hip_runtime.h>

// Problem dims (fixed by reference)
#define T_TOTAL (32 * 4096)   // B*S = 131072 tokens
#define FDIM 256
#define NG 2                  // groups
#define NN 128                // entries per group
#define DDIM 128              // group dim
#define EDIM 256              // embed dim

#define TAU 0.004f            // bf16x3-vs-f32 safety margin for argmax gap
#define CAP 16384             // max flagged (t,g) entries (expected ~1k)

typedef __attribute__((ext_vector_type(4))) float f32x4;
typedef __attribute__((ext_vector_type(8))) short short8;

// ---------------------------------------------------------------------------
// Kernel P (prep): CO = codebooks @ W_out slices ; BT = split-bf16 W^T ;
// zero flag counter. One block per (g,n) = 256 blocks x 256 threads.
// ---------------------------------------------------------------------------
__global__ __launch_bounds__(256) void prep_kernel(
    const float* __restrict__ codebooks,  // [2][128][128]
    const float* __restrict__ W_out,      // [256][256]
    const float* __restrict__ Wl,         // [2][128 k][128 n]
    float* __restrict__ CO,               // [2][128][256]
    short* __restrict__ BT,               // [2 lev][2 g][128 n][128 k]
    int* __restrict__ flag_count)
{
    const int gn  = blockIdx.x;           // g*128 + n
    const int g   = gn >> 7;
    const int tid = threadIdx.x;
    __shared__ float cb[DDIM];
    if (tid < DDIM) cb[tid] = codebooks[gn * DDIM + tid];
    if (tid >= 128) {
        const int k = tid - 128;
        const int n = gn & 127;
        const float x = Wl[((size_t)g * DDIM + k) * NN + n];
        const unsigned u = __float_as_uint(x);
        const float hi = __uint_as_float(u & 0xffff0000u);
        const unsigned u2 = __float_as_uint(x - hi);   // exact residual
        BT[(size_t)g * 16384 + n * 128 + k] = (short)(u >> 16);
        BT[32768 + (size_t)g * 16384 + n * 128 + k] = (short)(u2 >> 16);
    }
    if (gn == 0 && tid == 0) *flag_count = 0;
    __syncthreads();
    float acc = 0.f;
    const float* wcol = W_out + (g * DDIM) * EDIM + tid;
#pragma unroll 4
    for (int d = 0; d < DDIM; ++d) acc += cb[d] * wcol[d * EDIM];
    CO[gn * EDIM + tid] = acc;
}

// ---------------------------------------------------------------------------
// Kernel M (fused main): block = 1024 threads = 16 waves = 2 groups x 8
// n-tiles; 128 contiguous tokens over 8 iterations (16 tokens/iter).
// Each wave holds its ENTIRE pre-split W fragment set in registers
// (8 x short8 = 32 VGPR, loaded once from L2-resident BT) -> the main loop
// has NO LDS reads and NO barriers; waves run independently, posting per-iter
// top-2 partials to LDS. One __syncthreads, 256-thread combine (idx+flag),
// then block-wide fused out gather-write. 1024-thr block forces VGPR<=128;
// per-thread live set ~95 regs (spill tripwire: WRITE_SIZE).
// ---------------------------------------------------------------------------
__global__ __launch_bounds__(1024) void pq_fused2_kernel(
    const float* __restrict__ features,   // [T][256]
    const float* __restrict__ gumbel,     // [T][2][128]
    const short* __restrict__ BT,         // [2 lev][2 g][128 n][128 k]
    const float* __restrict__ bl,         // [2][128]
    const float* __restrict__ CO,         // [2][128][256]
    const float* __restrict__ b_out,      // [256]
    float* __restrict__ out,              // [T][256]
    float* __restrict__ idx_f,            // [T][2] float-encoded indices
    int* __restrict__ flag_count,
    int* __restrict__ flag_list)
{
    __shared__ float pm1[8][2][8][16];    // [it][g][nt][q] 8 KB
    __shared__ float pm2[8][2][8][16];    // 8 KB
    __shared__ int   pi1[8][2][8][16];    // 8 KB
    __shared__ int   sidx[2][128];        // 1 KB

    const int tid = threadIdx.x;
    const int w   = tid >> 6;       // wave 0..15
    const int g   = w >> 3;         // group
    const int nt  = w & 7;          // n-tile
    const int l   = tid & 63;
    const int q   = l & 15;         // token slot / A-row
    const int h   = l >> 4;         // k-octet / D-subrow
    const int n0  = nt * 16;
    const int tb0 = blockIdx.x * 128;

    // ---- persistent W fragments: lane (q,h) holds W[n0+q][ks*32+h*8 ..+7]
    const short* bt1 = BT + (size_t)g * 16384 + (n0 + q) * 128 + h * 8;
    short8 A1[4], A2[4];
#pragma unroll
    for (int ks = 0; ks < 4; ++ks) {
        A1[ks] = *reinterpret_cast<const short8*>(bt1 + ks * 32);
        A2[ks] = *reinterpret_cast<const short8*>(bt1 + 32768 + ks * 32);
    }
    const f32x4 bv = *reinterpret_cast<const f32x4*>(bl + g * NN + n0 + h * 4);

    for (int it = 0; it < 8; ++it) {
        const int t = tb0 + it * 16 + q;
        // gumbel for this lane's 4 n-values (issued early, consumed at epilogue)
        const f32x4 G = *reinterpret_cast<const f32x4*>(
            gumbel + ((size_t)t * NG + g) * NN + n0 + h * 4);
        // features: full half-row k-slices for this lane (L1-shared across waves)
        const float* fp = features + (size_t)t * FDIM + g * DDIM + h * 8;
        f32x4 FA[8];
#pragma unroll
        for (int j = 0; j < 8; ++j)
            FA[j] = *reinterpret_cast<const f32x4*>(fp + (j >> 1) * 32 + (j & 1) * 4);

        f32x4 acc = (f32x4){0.f, 0.f, 0.f, 0.f};
#pragma unroll
        for (int ks = 0; ks < 4; ++ks) {
            short8 B1, B2;
#pragma unroll
            for (int e = 0; e < 4; ++e) {
                const unsigned ua = __float_as_uint(FA[2 * ks][e]);
                const float ha = __uint_as_float(ua & 0xffff0000u);
                const unsigned ra = __float_as_uint(FA[2 * ks][e] - ha);
                B1[e] = (short)(ua >> 16);
                B2[e] = (short)(ra >> 16);
                const unsigned ub = __float_as_uint(FA[2 * ks + 1][e]);
                const float hb = __uint_as_float(ub & 0xffff0000u);
                const unsigned rb = __float_as_uint(FA[2 * ks + 1][e] - hb);
                B1[4 + e] = (short)(ub >> 16);
                B2[4 + e] = (short)(rb >> 16);
            }
            acc = __builtin_amdgcn_mfma_f32_16x16x32_bf16(A1[ks], B1, acc, 0, 0, 0);
            acc = __builtin_amdgcn_mfma_f32_16x16x32_bf16(A2[ks], B1, acc, 0, 0, 0);
            acc = __builtin_amdgcn_mfma_f32_16x16x32_bf16(A1[ks], B2, acc, 0, 0, 0);
        }

        // ---- per-lane top-2 over 4 n-values, then reduce across the 4 h-lanes
        float m1 = -3.4e38f, m2 = -3.4e38f;
        int   i1 = 0;
#pragma unroll
        for (int r = 0; r < 4; ++r) {
            const float vv = acc[r] + bv[r] + G[r];
            const int   n  = n0 + h * 4 + r;
            if (vv > m1) { m2 = m1; m1 = vv; i1 = n; }
            else         { m2 = fmaxf(m2, vv); }
        }
#pragma unroll
        for (int off = 16; off < 64; off <<= 1) {
            const float om1 = __shfl_xor(m1, off);
            const int   oi1 = __shfl_xor(i1, off);
            const float om2 = __shfl_xor(m2, off);
            if (om1 > m1)      { m2 = fmaxf(m1, om2); m1 = om1; i1 = oi1; }
            else if (om1 < m1) { m2 = fmaxf(m2, om1); }
            else               { m2 = m1; i1 = min(i1, oi1); }
        }
        if (h == 0) {
            pm1[it][g][nt][q] = m1;
            pm2[it][g][nt][q] = m2;
            pi1[it][g][nt][q] = i1;
        }
    }
    __syncthreads();

    // ---- combine 8 n-tile partials per (it, g, token): 256 threads
    if (tid < 256) {
        const int it  = tid >> 5;
        const int gg  = (tid >> 4) & 1;
        const int tok = tid & 15;
        float c1 = pm1[it][gg][0][tok], c2 = pm2[it][gg][0][tok];
        int   ci = pi1[it][gg][0][tok];
#pragma unroll
        for (int p = 1; p < 8; ++p) {
            const float a1 = pm1[it][gg][p][tok];
            const float a2 = pm2[it][gg][p][tok];
            const int   ai = pi1[it][gg][p][tok];
            if (a1 > c1)      { c2 = fmaxf(c1, a2); c1 = a1; ci = ai; }
            else if (a1 < c1) { c2 = fmaxf(c2, a1); }
            else              { c2 = c1; ci = min(ci, ai); }
        }
        const int tglob = tb0 + it * 16 + tok;
        idx_f[(size_t)tglob * NG + gg] = (float)ci;
        sidx[gg][it * 16 + tok] = ci;
        if (c1 - c2 < TAU) {
            const int p = atomicAdd(flag_count, 1);
            if (p < CAP) flag_list[p] = tglob * NG + gg;
        }
    }
    __syncthreads();

    // ---- fused out write: 8 threads per token, 8 float4 slots each
    {
        const int tok = tid >> 3;       // 0..127
        const int c   = tid & 7;
        const int i0  = sidx[0][tok];
        const int j1  = sidx[1][tok];
        const float* c0p = CO + (size_t)i0 * EDIM;
        const float* c1p = CO + (size_t)(NN + j1) * EDIM;
        float* op = out + (size_t)(tb0 + tok) * EDIM;
#pragma unroll
        for (int jj = 0; jj < 8; ++jj) {
            const int e4 = c + jj * 8;
            const float4 a  = *reinterpret_cast<const float4*>(c0p + e4 * 4);
            const float4 b2 = *reinterpret_cast<const float4*>(c1p + e4 * 4);
            const float4 bo = *reinterpret_cast<const float4*>(b_out + e4 * 4);
            float4 o;
            o.x = a.x + b2.x + bo.x;
            o.y = a.y + b2.y + bo.y;
            o.z = a.z + b2.z + bo.z;
            o.w = a.w + b2.w + bo.w;
            *reinterpret_cast<float4*>(op + e4 * 4) = o;
        }
    }
}

// ---------------------------------------------------------------------------
// Kernel F (fixup): exact sequential-f32 fmaf recompute for flagged (t,g).
// ---------------------------------------------------------------------------
__global__ __launch_bounds__(128) void fixup_kernel(
    const float* __restrict__ features,
    const float* __restrict__ gumbel,
    const float* __restrict__ Wl,         // [2][128 k][128 n]
    const float* __restrict__ bl,
    float* __restrict__ idx_f,
    const int* __restrict__ flag_count,
    const int* __restrict__ flag_list)
{
    __shared__ float sm[2];
    __shared__ int   si[2];
    int total = *flag_count;
    if (total > CAP) total = CAP;
    const int n = threadIdx.x;

    for (int e = blockIdx.x; e < total; e += gridDim.x) {
        const int code = flag_list[e];
        const int t = code >> 1, g = code & 1;
        const float* fpr = features + (size_t)t * FDIM + g * DDIM;
        const float* wp  = Wl + (size_t)g * DDIM * NN + n;
        float dot = 0.f;
#pragma unroll 8
        for (int k = 0; k < DDIM; ++k) dot = fmaf(fpr[k], wp[(size_t)k * NN], dot);
        const float v = (dot + bl[g * NN + n]) + gumbel[((size_t)t * NG + g) * NN + n];

        float m = v; int bi = n;
#pragma unroll
        for (int off = 1; off < 64; off <<= 1) {
            const float om = __shfl_xor(m, off);
            const int   ob = __shfl_xor(bi, off);
            if (om > m || (om == m && ob < bi)) { m = om; bi = ob; }
        }
        if ((n & 63) == 0) { sm[n >> 6] = m; si[n >> 6] = bi; }
        __syncthreads();
        if (n == 0) {
            const float mA = sm[0], mB = sm[1];
            const int bA = si[0], bB = si[1];
            const int best = (mB > mA || (mB == mA && bB < bA)) ? bB : bA;
            idx_f[code] = (float)best;
        }
        __syncthreads();
    }
}

// ---------------------------------------------------------------------------
// Kernel X (outfix): rewrite out rows for flagged tokens from FINAL indices.
// Duplicate tokens (both groups flagged) write identical bytes — benign.
// ---------------------------------------------------------------------------
__global__ __launch_bounds__(64) void outfix_kernel(
    const float* __restrict__ CO,
    const float* __restrict__ b_out,
    const float* __restrict__ idx_f,
    const int* __restrict__ flag_count,
    const int* __restrict__ flag_list,
    float* __restrict__ out)
{
    int total = *flag_count;
    if (total > CAP) total = CAP;
    const int c = threadIdx.x;    // 0..63 float4 slots

    for (int e = blockIdx.x; e < total; e += gridDim.x) {
        const int t  = flag_list[e] >> 1;
        const int i0 = (int)idx_f[t * NG + 0];
        const int i1 = (int)idx_f[t * NG + 1];
        const float4 a  = *reinterpret_cast<const float4*>(CO + (size_t)i0 * EDIM + c * 4);
        const float4 b2 = *reinterpret_cast<const float4*>(CO + (size_t)(NN + i1) * EDIM + c * 4);
        const float4 bo = *reinterpret_cast<const float4*>(b_out + c * 4);
        float4 o;
        o.x = a.x + b2.x + bo.x;
        o.y = a.y + b2.y + bo.y;
        o.z = a.z + b2.z + bo.z;
        o.w = a.w + b2.w + bo.w;
        *reinterpret_cast<float4*>(out + (size_t)t * EDIM + c * 4) = o;
    }
}

// ---------------------------------------------------------------------------
extern "C" void kernel_launch(void* const* d_in, const int* in_sizes, int n_in,
                              void* d_out, int out_size, void* d_ws, size_t ws_size,
                              hipStream_t stream) {
    const float* features  = (const float*)d_in[0];  // [32,4096,256]
    const float* gumbel    = (const float*)d_in[1];  // [32,4096,2,128]
    const float* Wl        = (const float*)d_in[2];  // [2,128,128]
    const float* bl        = (const float*)d_in[3];  // [2,128]
    const float* codebooks = (const float*)d_in[4];  // [2,128,128]
    const float* W_out     = (const float*)d_in[5];  // [256,256]
    const float* b_out     = (const float*)d_in[6];  // [256]

    float* out   = (float*)d_out;                    // [T,256]
    float* idx_f = out + (size_t)T_TOTAL * EDIM;     // [T,2] float-encoded indices

    // ws layout: CO (256KB) | BT (128KB) | flag_count (pad 256B) | flag_list (64KB)
    char* ws = (char*)d_ws;
    float* CO         = (float*)ws;                        // 262144 B
    short* BT         = (short*)(ws + 262144);             // 131072 B
    int*   flag_count = (int*)(ws + 262144 + 131072);      // @393216
    int*   flag_list  = (int*)(ws + 393216 + 256);         // @393472, 64KB

    prep_kernel<<<NG * NN, 256, 0, stream>>>(codebooks, W_out, Wl, CO, BT, flag_count);
    pq_fused2_kernel<<<T_TOTAL / 128, 1024, 0, stream>>>(
        features, gumbel, BT, bl, CO, b_out, out, idx_f, flag_count, flag_list);
    fixup_kernel<<<1024, 128, 0, stream>>>(
        features, gumbel, Wl, bl, idx_f, flag_count, flag_list);
    outfix_kernel<<<1024, 64, 0, stream>>>(
        CO, b_out, idx_f, flag_count, flag_list, out);
}

// Round 11
// 132.300 us; speedup vs baseline: 1.9917x; 1.5870x over previous
//
#include <hip/hip_runtime.h>

// Problem dims (fixed by reference)
#define T_TOTAL (32 * 4096)   // B*S = 131072 tokens
#define FDIM 256
#define NG 2                  // groups
#define NN 128                // entries per group
#define DDIM 128              // group dim
#define EDIM 256              // embed dim

#define TAU 0.004f            // bf16x3-vs-f32 safety margin for argmax gap
#define CAP 16384             // max flagged (t,g) entries (expected ~1k)

typedef __attribute__((ext_vector_type(4))) float f32x4;
typedef __attribute__((ext_vector_type(8))) short short8;

// ---------------------------------------------------------------------------
// Kernel P (prep): CO = codebooks @ W_out slices ; BT = split-bf16 W^T ;
// zero flag counter. One block per (g,n) = 256 blocks x 256 threads.
// ---------------------------------------------------------------------------
__global__ __launch_bounds__(256) void prep_kernel(
    const float* __restrict__ codebooks,  // [2][128][128]
    const float* __restrict__ W_out,      // [256][256]
    const float* __restrict__ Wl,         // [2][128 k][128 n]
    float* __restrict__ CO,               // [2][128][256]
    short* __restrict__ BT,               // [2 lev][2 g][128 n][128 k]
    int* __restrict__ flag_count)
{
    const int gn  = blockIdx.x;           // g*128 + n
    const int g   = gn >> 7;
    const int tid = threadIdx.x;
    __shared__ float cb[DDIM];
    if (tid < DDIM) cb[tid] = codebooks[gn * DDIM + tid];
    if (tid >= 128) {
        const int k = tid - 128;
        const int n = gn & 127;
        const float x = Wl[((size_t)g * DDIM + k) * NN + n];
        const unsigned u = __float_as_uint(x);
        const float hi = __uint_as_float(u & 0xffff0000u);
        const unsigned u2 = __float_as_uint(x - hi);   // exact residual
        BT[(size_t)g * 16384 + n * 128 + k] = (short)(u >> 16);
        BT[32768 + (size_t)g * 16384 + n * 128 + k] = (short)(u2 >> 16);
    }
    if (gn == 0 && tid == 0) *flag_count = 0;
    __syncthreads();
    float acc = 0.f;
    const float* wcol = W_out + (g * DDIM) * EDIM + tid;
#pragma unroll 4
    for (int d = 0; d < DDIM; ++d) acc += cb[d] * wcol[d * EDIM];
    CO[gn * EDIM + tid] = acc;
}

// ---------------------------------------------------------------------------
// Kernel M (main v11): one block = 512 thr = 8 waves, ONE group, 256 tokens
// over 4 stages of 64. Per stage:
//   [issue F global loads (4 x f32x4/thread, transient)]
//   [combine prev stage's per-wave top-2 partials (tid<64), write idx+flag]
//   [split f32 -> 2 bf16 planes]  [barrier]  [ds_write 32KB F-LDS, swizzled]
//   [barrier]  [4 x 16-token MFMA subtiles: B from LDS, W(16n) in 32 regs]
// Per-wave live set ~70 regs -> waves provide the MLP (24-28 waves/CU).
// F split happens ONCE per token (no redundancy). Numerics identical to r5-10.
// ---------------------------------------------------------------------------
__global__ __launch_bounds__(512) void pq_v11_kernel(
    const float* __restrict__ features,   // [T][256]
    const float* __restrict__ gumbel,     // [T][2][128]
    const short* __restrict__ BT,         // [2 lev][2 g][128 n][128 k]
    const float* __restrict__ bl,         // [2][128]
    float* __restrict__ idx_f,            // [T][2] float-encoded indices
    int* __restrict__ flag_count,
    int* __restrict__ flag_list)
{
    __shared__ short8 Flds[2048];         // 32 KB: [lev][tok][chunk ^ (tok&7)]
    __shared__ float pm1s[8][64];
    __shared__ float pm2s[8][64];
    __shared__ int   pi1s[8][64];

    const int tid  = threadIdx.x;
    const int g    = blockIdx.x & 1;
    const int span = blockIdx.x >> 1;     // 0..511
    const int w    = tid >> 6;            // wave = n-tile 0..7
    const int l    = tid & 63;
    const int q    = l & 15;              // token col / A row
    const int h    = l >> 4;              // k-octet / D-subrow
    const int n0   = w * 16;
    const int tb0  = span * 256;

    // ---- persistent W fragments: lane (q,h) holds W[n0+q][ks*32+h*8..+7]
    const short* bt1 = BT + (size_t)g * 16384 + (n0 + q) * 128 + h * 8;
    short8 A1[4], A2[4];
#pragma unroll
    for (int ks = 0; ks < 4; ++ks) {
        A1[ks] = *reinterpret_cast<const short8*>(bt1 + ks * 32);
        A2[ks] = *reinterpret_cast<const short8*>(bt1 + 32768 + ks * 32);
    }
    const f32x4 bv = *reinterpret_cast<const f32x4*>(bl + g * NN + n0 + h * 4);

    // staging role: thread = (stok, skc)
    const int stok = tid >> 3;            // 0..63
    const int skc  = tid & 7;             // 0..7 (16-k chunks)
    const int swz  = stok & 7;

    for (int st = 0; st < 4; ++st) {
        const int t64 = tb0 + st * 64;

        // ---- issue this stage's F loads (64B contiguous per thread)
        const float* fp = features + (size_t)(t64 + stok) * FDIM + g * DDIM + skc * 16;
        const f32x4 F0 = *reinterpret_cast<const f32x4*>(fp);
        const f32x4 F1 = *reinterpret_cast<const f32x4*>(fp + 4);
        const f32x4 F2 = *reinterpret_cast<const f32x4*>(fp + 8);
        const f32x4 F3 = *reinterpret_cast<const f32x4*>(fp + 12);

        // ---- split to two bf16 planes (once per token)
        short8 SH0, SH1, SL0, SL1;
#pragma unroll
        for (int e = 0; e < 4; ++e) {
            unsigned u; float hi;
            u = __float_as_uint(F0[e]); hi = __uint_as_float(u & 0xffff0000u);
            SH0[e]     = (short)(u >> 16); SL0[e]     = (short)(__float_as_uint(F0[e] - hi) >> 16);
            u = __float_as_uint(F1[e]); hi = __uint_as_float(u & 0xffff0000u);
            SH0[4 + e] = (short)(u >> 16); SL0[4 + e] = (short)(__float_as_uint(F1[e] - hi) >> 16);
            u = __float_as_uint(F2[e]); hi = __uint_as_float(u & 0xffff0000u);
            SH1[e]     = (short)(u >> 16); SL1[e]     = (short)(__float_as_uint(F2[e] - hi) >> 16);
            u = __float_as_uint(F3[e]); hi = __uint_as_float(u & 0xffff0000u);
            SH1[4 + e] = (short)(u >> 16); SL1[4 + e] = (short)(__float_as_uint(F3[e] - hi) >> 16);
        }

        __syncthreads();   // prev compute done (F-LDS reads, pm writes)

        // ---- combine previous stage's partials while staging is in flight
        if (st > 0 && tid < 64) {
            float c1 = pm1s[0][tid], c2 = pm2s[0][tid];
            int   ci = pi1s[0][tid];
#pragma unroll
            for (int p = 1; p < 8; ++p) {
                const float a1 = pm1s[p][tid];
                const float a2 = pm2s[p][tid];
                const int   ai = pi1s[p][tid];
                if (a1 > c1)      { c2 = fmaxf(c1, a2); c1 = a1; ci = ai; }
                else if (a1 < c1) { c2 = fmaxf(c2, a1); }
                else              { c2 = c1; ci = min(ci, ai); }
            }
            const int t = tb0 + (st - 1) * 64 + tid;
            idx_f[(size_t)t * NG + g] = (float)ci;
            if (c1 - c2 < TAU) {
                const int p = atomicAdd(flag_count, 1);
                if (p < CAP) flag_list[p] = t * NG + g;
            }
        }

        // ---- ds_write the two planes, swizzled
        {
            short8* rowHi = Flds + stok * 16;
            short8* rowLo = Flds + 1024 + stok * 16;
            rowHi[(2 * skc)     ^ swz] = SH0;
            rowHi[(2 * skc + 1) ^ swz] = SH1;
            rowLo[(2 * skc)     ^ swz] = SL0;
            rowLo[(2 * skc + 1) ^ swz] = SL1;
        }
        __syncthreads();   // staging visible

        // ---- compute: 4 subtiles of 16 tokens
        for (int s = 0; s < 4; ++s) {
            const int t = t64 + s * 16 + q;
            const f32x4 G = *reinterpret_cast<const f32x4*>(
                gumbel + ((size_t)t * NG + g) * NN + n0 + h * 4);

            const int rbase = (s * 16 + q) * 16;
            f32x4 acc = (f32x4){0.f, 0.f, 0.f, 0.f};
#pragma unroll
            for (int ks = 0; ks < 4; ++ks) {
                const int ci0 = (ks * 4 + h) ^ (q & 7);
                const short8 B1 = Flds[rbase + ci0];
                const short8 B2 = Flds[1024 + rbase + ci0];
                acc = __builtin_amdgcn_mfma_f32_16x16x32_bf16(A1[ks], B1, acc, 0, 0, 0);
                acc = __builtin_amdgcn_mfma_f32_16x16x32_bf16(A2[ks], B1, acc, 0, 0, 0);
                acc = __builtin_amdgcn_mfma_f32_16x16x32_bf16(A1[ks], B2, acc, 0, 0, 0);
            }

            // per-lane top-2 over its 4 n-values
            float m1 = -3.4e38f, m2 = -3.4e38f;
            int   i1 = 0;
#pragma unroll
            for (int r = 0; r < 4; ++r) {
                const float vv = acc[r] + bv[r] + G[r];
                const int   n  = n0 + h * 4 + r;
                if (vv > m1) { m2 = m1; m1 = vv; i1 = n; }
                else         { m2 = fmaxf(m2, vv); }
            }
            // combine the 4 h-lanes sharing this token
#pragma unroll
            for (int off = 16; off < 64; off <<= 1) {
                const float om1 = __shfl_xor(m1, off);
                const int   oi1 = __shfl_xor(i1, off);
                const float om2 = __shfl_xor(m2, off);
                if (om1 > m1)      { m2 = fmaxf(m1, om2); m1 = om1; i1 = oi1; }
                else if (om1 < m1) { m2 = fmaxf(m2, om1); }
                else               { m2 = m1; i1 = min(i1, oi1); }
            }
            if (h == 0) {
                pm1s[w][s * 16 + q] = m1;
                pm2s[w][s * 16 + q] = m2;
                pi1s[w][s * 16 + q] = i1;
            }
        }
    }

    // ---- final combine for stage 3
    __syncthreads();
    if (tid < 64) {
        float c1 = pm1s[0][tid], c2 = pm2s[0][tid];
        int   ci = pi1s[0][tid];
#pragma unroll
        for (int p = 1; p < 8; ++p) {
            const float a1 = pm1s[p][tid];
            const float a2 = pm2s[p][tid];
            const int   ai = pi1s[p][tid];
            if (a1 > c1)      { c2 = fmaxf(c1, a2); c1 = a1; ci = ai; }
            else if (a1 < c1) { c2 = fmaxf(c2, a1); }
            else              { c2 = c1; ci = min(ci, ai); }
        }
        const int t = tb0 + 3 * 64 + tid;
        idx_f[(size_t)t * NG + g] = (float)ci;
        if (c1 - c2 < TAU) {
            const int p = atomicAdd(flag_count, 1);
            if (p < CAP) flag_list[p] = t * NG + g;
        }
    }
}

// ---------------------------------------------------------------------------
// Kernel F (fixup): exact sequential-f32 fmaf recompute for flagged (t,g).
// ---------------------------------------------------------------------------
__global__ __launch_bounds__(128) void fixup_kernel(
    const float* __restrict__ features,
    const float* __restrict__ gumbel,
    const float* __restrict__ Wl,         // [2][128 k][128 n]
    const float* __restrict__ bl,
    float* __restrict__ idx_f,
    const int* __restrict__ flag_count,
    const int* __restrict__ flag_list)
{
    __shared__ float sm[2];
    __shared__ int   si[2];
    int total = *flag_count;
    if (total > CAP) total = CAP;
    const int n = threadIdx.x;

    for (int e = blockIdx.x; e < total; e += gridDim.x) {
        const int code = flag_list[e];
        const int t = code >> 1, g = code & 1;
        const float* fpr = features + (size_t)t * FDIM + g * DDIM;
        const float* wp  = Wl + (size_t)g * DDIM * NN + n;
        float dot = 0.f;
#pragma unroll 8
        for (int k = 0; k < DDIM; ++k) dot = fmaf(fpr[k], wp[(size_t)k * NN], dot);
        const float v = (dot + bl[g * NN + n]) + gumbel[((size_t)t * NG + g) * NN + n];

        float m = v; int bi = n;
#pragma unroll
        for (int off = 1; off < 64; off <<= 1) {
            const float om = __shfl_xor(m, off);
            const int   ob = __shfl_xor(bi, off);
            if (om > m || (om == m && ob < bi)) { m = om; bi = ob; }
        }
        if ((n & 63) == 0) { sm[n >> 6] = m; si[n >> 6] = bi; }
        __syncthreads();
        if (n == 0) {
            const float mA = sm[0], mB = sm[1];
            const int bA = si[0], bB = si[1];
            const int best = (mB > mA || (mB == mA && bB < bA)) ? bB : bA;
            idx_f[code] = (float)best;
        }
        __syncthreads();
    }
}

// ---------------------------------------------------------------------------
// Kernel C: out[t][e] = CO[0][i0][e] + CO[1][i1][e] + b_out[e]
// ---------------------------------------------------------------------------
__global__ __launch_bounds__(256) void out_kernel(
    const float* __restrict__ CO,      // [2][128][256]
    const float* __restrict__ b_out,   // [256]
    const float* __restrict__ idx_f,   // [T][2] float-encoded
    float* __restrict__ out)           // [T][256]
{
    const int tid = threadIdx.x;
    const int e4  = tid & 63;    // float4 index in e
    const int ts  = tid >> 6;    // 0..3
    const int tbase = blockIdx.x * 16;
    const float4 b = *reinterpret_cast<const float4*>(b_out + e4 * 4);

#pragma unroll
    for (int it = 0; it < 4; ++it) {
        const int t  = tbase + it * 4 + ts;
        const int i0 = (int)idx_f[t * NG + 0];
        const int i1 = (int)idx_f[t * NG + 1];
        const float4 c0 = *reinterpret_cast<const float4*>(CO + (size_t)i0 * EDIM + e4 * 4);
        const float4 c1 = *reinterpret_cast<const float4*>(CO + (size_t)(NN + i1) * EDIM + e4 * 4);
        float4 o;
        o.x = c0.x + c1.x + b.x;
        o.y = c0.y + c1.y + b.y;
        o.z = c0.z + c1.z + b.z;
        o.w = c0.w + c1.w + b.w;
        *reinterpret_cast<float4*>(out + (size_t)t * EDIM + e4 * 4) = o;
    }
}

// ---------------------------------------------------------------------------
extern "C" void kernel_launch(void* const* d_in, const int* in_sizes, int n_in,
                              void* d_out, int out_size, void* d_ws, size_t ws_size,
                              hipStream_t stream) {
    const float* features  = (const float*)d_in[0];  // [32,4096,256]
    const float* gumbel    = (const float*)d_in[1];  // [32,4096,2,128]
    const float* Wl        = (const float*)d_in[2];  // [2,128,128]
    const float* bl        = (const float*)d_in[3];  // [2,128]
    const float* codebooks = (const float*)d_in[4];  // [2,128,128]
    const float* W_out     = (const float*)d_in[5];  // [256,256]
    const float* b_out     = (const float*)d_in[6];  // [256]

    float* out   = (float*)d_out;                    // [T,256]
    float* idx_f = out + (size_t)T_TOTAL * EDIM;     // [T,2] float-encoded indices

    // ws layout: CO (256KB) | BT (128KB) | flag_count (pad 256B) | flag_list (64KB)
    char* ws = (char*)d_ws;
    float* CO         = (float*)ws;                        // 262144 B
    short* BT         = (short*)(ws + 262144);             // 131072 B
    int*   flag_count = (int*)(ws + 262144 + 131072);      // @393216
    int*   flag_list  = (int*)(ws + 393216 + 256);         // @393472, 64KB

    prep_kernel<<<NG * NN, 256, 0, stream>>>(codebooks, W_out, Wl, CO, BT, flag_count);
    pq_v11_kernel<<<1024, 512, 0, stream>>>(
        features, gumbel, BT, bl, idx_f, flag_count, flag_list);
    fixup_kernel<<<1024, 128, 0, stream>>>(
        features, gumbel, Wl, bl, idx_f, flag_count, flag_list);
    out_kernel<<<T_TOTAL / 16, 256, 0, stream>>>(CO, b_out, idx_f, out);
}